// Round 2
// baseline (11903.189 us; speedup 1.0000x reference)
//
#include <hip/hip_runtime.h>
#include <math.h>

#define EPT 4  // edges processed concurrently per wave

__device__ __forceinline__ float silu_f(float v) { return v / (1.0f + __expf(-v)); }

// wave-per-edge-group: lane j owns output feature j; EPT edges share each LDS
// weight read via v_readlane broadcasts.
// LDS: W1 rows 1..127 (f32) + W2 + W3 = 65280 B (rows 0 & 128 of W1 in regs).
__global__ __launch_bounds__(256) void egnn_edge_kernel(
    const float* __restrict__ x,
    const float* __restrict__ hh,
    const int* __restrict__ src_idx,
    const int* __restrict__ dst_idx,
    const float* __restrict__ W1, const float* __restrict__ b1,
    const float* __restrict__ W2, const float* __restrict__ b2,
    const float* __restrict__ W3, const float* __restrict__ b3,
    const float* __restrict__ W4,
    float* __restrict__ out_radial,   // [E]
    float* __restrict__ out_trans,    // [E,3]
    float* __restrict__ out_ef,       // [E,64]
    int n_edges)
{
    __shared__ float sW1[127 * 64];   // W1 rows 1..127   (32768-256 B)
    __shared__ float sW2[64 * 64];    // 16384 B
    __shared__ float sW3[64 * 64];    // 16384 B          -> 65280 B total

    const int tid = threadIdx.x;
    for (int i = tid; i < 127 * 64; i += 256) sW1[i] = W1[64 + i];
    for (int i = tid; i < 64 * 64; i += 256) { sW2[i] = W2[i]; sW3[i] = W3[i]; }
    __syncthreads();

    const int lane = tid & 63;
    const float w1r    = W1[lane];             // W1 row 0   (radial)
    const float w1last = W1[128 * 64 + lane];  // W1 row 128 (hd[63])
    const float b1l = b1[lane], b2l = b2[lane], b3l = b3[lane];
    const float w4l = W4[lane];

    const int  wave = tid >> 6;
    const long wid  = (long)blockIdx.x * 4 + wave;
    const long wtot = (long)gridDim.x * 4;
    const long ngrp = ((long)n_edges + EPT - 1) / EPT;

    for (long g = wid; g < ngrp; g += wtot) {
        const long e0 = g * EPT;

        float hs[EPT], hd[EPT], dx0[EPT], dx1[EPT], dx2[EPT], radial[EPT];
        #pragma unroll
        for (int i = 0; i < EPT; ++i) {
            long e = e0 + i; if (e >= n_edges) e = n_edges - 1;  // clamp tail
            const int s = src_idx[e];
            const int d = dst_idx[e];
            hs[i] = hh[(long)s * 64 + lane];
            hd[i] = hh[(long)d * 64 + lane];
            dx0[i] = x[s * 3 + 0] - x[d * 3 + 0];
            dx1[i] = x[s * 3 + 1] - x[d * 3 + 1];
            dx2[i] = x[s * 3 + 2] - x[d * 3 + 2];
            radial[i] = dx0[i] * dx0[i] + dx1[i] * dx1[i] + dx2[i] * dx2[i];
        }

        // ---- layer 1: h1 = silu([radial, hs, hd] @ W1 + b1) ----
        float acc[EPT];
        #pragma unroll
        for (int i = 0; i < EPT; ++i) acc[i] = b1l + radial[i] * w1r;
        #pragma unroll
        for (int k = 0; k < 64; ++k) {
            const float w = sW1[k * 64 + lane];            // W1 row 1+k
            #pragma unroll
            for (int i = 0; i < EPT; ++i) acc[i] += __shfl(hs[i], k) * w;
        }
        #pragma unroll
        for (int k = 0; k < 63; ++k) {
            const float w = sW1[(64 + k) * 64 + lane];     // W1 row 65+k
            #pragma unroll
            for (int i = 0; i < EPT; ++i) acc[i] += __shfl(hd[i], k) * w;
        }
        #pragma unroll
        for (int i = 0; i < EPT; ++i) acc[i] += __shfl(hd[i], 63) * w1last;
        float h1[EPT];
        #pragma unroll
        for (int i = 0; i < EPT; ++i) h1[i] = silu_f(acc[i]);

        // ---- layer 2: ef = silu(h1 @ W2 + b2) ----
        float ef[EPT];
        #pragma unroll
        for (int i = 0; i < EPT; ++i) acc[i] = b2l;
        #pragma unroll
        for (int k = 0; k < 64; ++k) {
            const float w = sW2[k * 64 + lane];
            #pragma unroll
            for (int i = 0; i < EPT; ++i) acc[i] += __shfl(h1[i], k) * w;
        }
        #pragma unroll
        for (int i = 0; i < EPT; ++i) ef[i] = silu_f(acc[i]);

        // ---- layer 3: h3 = silu(ef @ W3 + b3) ----
        float h3[EPT];
        #pragma unroll
        for (int i = 0; i < EPT; ++i) acc[i] = b3l;
        #pragma unroll
        for (int k = 0; k < 64; ++k) {
            const float w = sW3[k * 64 + lane];
            #pragma unroll
            for (int i = 0; i < EPT; ++i) acc[i] += __shfl(ef[i], k) * w;
        }
        #pragma unroll
        for (int i = 0; i < EPT; ++i) h3[i] = silu_f(acc[i]);

        // ---- layer 4: scale = tanh(h3 @ W4) ----
        float scale[EPT];
        #pragma unroll
        for (int i = 0; i < EPT; ++i) {
            float p = h3[i] * w4l;
            #pragma unroll
            for (int off = 32; off > 0; off >>= 1) p += __shfl_xor(p, off);
            scale[i] = tanhf(p);
        }

        // ---- stores ----
        #pragma unroll
        for (int i = 0; i < EPT; ++i) {
            const long e = e0 + i;
            if (e < n_edges) {
                out_ef[e * 64 + lane] = ef[i];
                if (lane == 0) out_radial[e] = radial[i];
                if (lane < 3) {
                    const float inv = 1.0f / (sqrtf(radial[i]) + 1e-8f);
                    const float dd = (lane == 0) ? dx0[i] : ((lane == 1) ? dx1[i] : dx2[i]);
                    out_trans[e * 3 + lane] = dd * inv * scale[i];
                }
            }
        }
    }
}

extern "C" void kernel_launch(void* const* d_in, const int* in_sizes, int n_in,
                              void* d_out, int out_size, void* d_ws, size_t ws_size,
                              hipStream_t stream) {
    const float* x   = (const float*)d_in[0];
    const float* hh  = (const float*)d_in[1];
    const int* src_idx = (const int*)d_in[2];
    const int* dst_idx = (const int*)d_in[3];
    const float* W1  = (const float*)d_in[4];
    const float* b1  = (const float*)d_in[5];
    const float* W2  = (const float*)d_in[6];
    const float* b2  = (const float*)d_in[7];
    const float* W3  = (const float*)d_in[8];
    const float* b3  = (const float*)d_in[9];
    const float* W4  = (const float*)d_in[10];

    const int E = in_sizes[2];

    float* out_radial = (float*)d_out;            // [E]
    float* out_trans  = out_radial + (long)E;     // [E,3]
    float* out_ef     = out_radial + (long)E * 4; // [E,64]

    dim3 grid(512), block(256);
    egnn_edge_kernel<<<grid, block, 0, stream>>>(
        x, hh, src_idx, dst_idx, W1, b1, W2, b2, W3, b3, W4,
        out_radial, out_trans, out_ef, E);
}